// Round 9
// baseline (265.544 us; speedup 1.0000x reference)
//
#include <hip/hip_runtime.h>

// LNCC, separable 5-tap Gaussian (sigma=1), fused single pass.
// (N=2, C=1, D=160, H=192, W=224) fp32 -> scalar.
// R14: R11 champion base (115-117us; 1344 blocks, 640 thr, 32x16x20 tile,
//      dbuf LDS, packed-fp32 v2f, lgkm-only barrier, monolithic predicated
//      loop -- peeling regresses 35%: R10+R13 both 148-156us @ 34% VALU).
//      ONE change: H-blur pairs output rows. Threads r<8 compute rows 2r,2r+1
//      from 6 shared taps (6x(b128+b32) per 2 rows, was 5x(b128+b32) per row).
//      LDS unit is the binding pipe (~1460 cyc/block-interval vs VALU
//      450/SIMD; ~85% busy) -> block LDS-cycles drop ~20%. Waves 0-3 carry
//      two D-pipelines (+20 VGPR, target <=64); waves 4-9 stage+wblur only
//      (wave-uniform branch). Geometry/loop untouched.

#define NB 2
#define DD 160
#define HH 192
#define WW 224
#define SH 224
#define SD (224*192)
#define SN (224*192*160)

#define TW 32
#define TH 16
#define ROWS (TH+4)          // 20
#define DCHUNK 20
#define NCHUNK (DD/DCHUNK)   // 8

#define K0 0.05448868f
#define K1 0.24420134f
#define K2 0.40261995f

typedef float v2f __attribute__((ext_vector_type(2)));
typedef float v4f __attribute__((ext_vector_type(4)));

__global__ __launch_bounds__(640) void lncc_main(
    const float* __restrict__ A, const float* __restrict__ B,
    const float* __restrict__ M, double* __restrict__ acc)
{
    __shared__ v2f  sIJ[2][ROWS][36];   // raw (I,J) + W halo, dbuf
    __shared__ v4f  wbA[2][ROWS][32];   // (bI,bJ,bII,bJJ), dbuf
    __shared__ float wbC[2][ROWS][32];  // bIJ, dbuf
    __shared__ float redL[10], redM[10];

    const int wt = blockIdx.x;           // 0..6
    const int ht = blockIdx.y;           // 0..11
    const int zz = blockIdx.z;           // 0..15
    const int n  = zz >> 3;
    const int dc = zz & 7;
    const int w0 = wt * TW, h0 = ht * TH, d0 = dc * DCHUNK;

    const float* __restrict__ Ai = A + (size_t)n * SN;
    const float* __restrict__ Bi = B + (size_t)n * SN;
    const float* __restrict__ Mi = M + (size_t)n * SN;

    const int tid = threadIdx.x;
    const int r   = tid >> 5;            // 0..19
    const int c   = tid & 31;            // 0..31

    // ---- staging addressing (per staged row r, unchanged from R11) ----
    const int gh  = h0 + r - 2;
    const bool hv = (unsigned)gh < (unsigned)HH;
    const int ghc = hv ? gh : 0;
    const int hwm = ghc * SH + (w0 + c);          // 32-bit offsets
    const int gwl = w0 + c - 2, gwr = w0 + c + 2;
    const bool lv = hv && (c < 2)   && (gwl >= 0);
    const bool rv = hv && (c >= 30) && (gwr < WW);
    const bool anyh = lv || rv;
    const int hwh = ghc * SH + (lv ? gwl : (rv ? gwr : 0));

    // ---- output addressing (threads r<8 own output rows 2r, 2r+1) ----
    const int ra = 2 * r;                // pair base row (valid for r<8)
    const int mbasea = (h0 + ra) * SH + (w0 + c);
    const int mbaseb = mbasea + SH;
    const bool prow = (r < 8);           // wave-uniform: waves 0-3

    // D-direction shift-register pipelines, output rows a and b
    v2f pP0a=0.f,pP1a=0.f,pP2a=0.f,pP3a=0.f;   // (bI,bJ)   row a
    v2f pQ0a=0.f,pQ1a=0.f,pQ2a=0.f,pQ3a=0.f;   // (bII,bJJ) row a
    float pC0a=0.f,pC1a=0.f,pC2a=0.f,pC3a=0.f; // bIJ       row a
    v2f pP0b=0.f,pP1b=0.f,pP2b=0.f,pP3b=0.f;
    v2f pQ0b=0.f,pQ1b=0.f,pQ2b=0.f,pQ3b=0.f;
    float pC0b=0.f,pC1b=0.f,pC2b=0.f,pC3b=0.f;
    float accL = 0.f, accM = 0.f;

    // prefetch registers for the slice staged at iteration k
    v2f nM = 0.f, nH = 0.f;
    {
        const int dd = d0 - 2;
        if (dd >= 0) {
            const int dof = dd * SD;
            if (hv)   { nM.x = Ai[dof + hwm]; nM.y = Bi[dof + hwm]; }
            if (anyh) { nH.x = Ai[dof + hwh]; nH.y = Bi[dof + hwh]; }
        }
    }

    const int NIT = DCHUNK + 6;          // 26
#pragma unroll 2
    for (int k = 0; k < NIT; ++k) {
        const int pw = k & 1;            // parity staged THIS iter
        const int px = pw ^ 1;

        // ---- W: stage prefetched raw slice (slices d0-2 .. d0+DCHUNK+1) ----
        if (k < DCHUNK + 4) {
            sIJ[pw][r][c + 2] = nM;
            if (c < 2)        sIJ[pw][r][c]     = nH;
            else if (c >= 30) sIJ[pw][r][c + 4] = nH;
        }

        // ---- prefetch slice k+1 ----
        nM = 0.f; nH = 0.f;
        {
            const int dd = d0 - 1 + k;
            if ((k + 1 < DCHUNK + 4) && (dd >= 0) && (dd < DD)) {
                const int dof = dd * SD;
                if (hv)   { nM.x = Ai[dof + hwm]; nM.y = Bi[dof + hwm]; }
                if (anyh) { nH.x = Ai[dof + hwh]; nH.y = Bi[dof + hwh]; }
            }
        }

        // ---- this iteration's mask values (pair rows) ----
        const int  dout = d0 - 6 + k;
        const bool outv = (k >= 6) && prow;
        float mvala = 0.f, mvalb = 0.f;
        if (outv) {
            mvala = Mi[dout * SD + mbasea];
            mvalb = Mi[dout * SD + mbaseb];
        }

        // ---- X: W-blur of slice staged last iteration (packed I/J) ----
        if (k >= 1 && k <= DCHUNK + 4) {
            const v2f v0 = sIJ[px][r][c];
            const v2f v1 = sIJ[px][r][c + 1];
            const v2f v2 = sIJ[px][r][c + 2];
            const v2f v3 = sIJ[px][r][c + 3];
            const v2f v4 = sIJ[px][r][c + 4];
            const v2f b  = K0*(v0+v4) + K1*(v1+v3) + K2*v2;           // (bI,bJ)
            const v2f bs = K0*(v0*v0+v4*v4) + K1*(v1*v1+v3*v3) + K2*(v2*v2); // (bII,bJJ)
            const float bij = K0*(v0.x*v0.y+v4.x*v4.y) + K1*(v1.x*v1.y+v3.x*v3.y) + K2*(v2.x*v2.y);
            wbA[px][r][c] = (v4f){b.x, b.y, bs.x, bs.y};
            wbC[px][r][c] = bij;
        }

        // ---- Y: H-blur, 6 taps -> 2 output rows (threads r<8) + D-pipes ----
        if (k >= 2 && prow) {
            const v4f a0 = wbA[pw][ra    ][c];
            const v4f a1 = wbA[pw][ra + 1][c];
            const v4f a2 = wbA[pw][ra + 2][c];
            const v4f a3 = wbA[pw][ra + 3][c];
            const v4f a4 = wbA[pw][ra + 4][c];
            const v4f a5 = wbA[pw][ra + 5][c];
            const float e0 = wbC[pw][ra    ][c];
            const float e1 = wbC[pw][ra + 1][c];
            const float e2 = wbC[pw][ra + 2][c];
            const float e3 = wbC[pw][ra + 3][c];
            const float e4 = wbC[pw][ra + 4][c];
            const float e5 = wbC[pw][ra + 5][c];

            const v2f h1a = K0*(a0.xy+a4.xy) + K1*(a1.xy+a3.xy) + K2*a2.xy;
            const v2f h2a = K0*(a0.zw+a4.zw) + K1*(a1.zw+a3.zw) + K2*a2.zw;
            const float hca = K0*(e0+e4) + K1*(e1+e3) + K2*e2;

            const v2f h1b = K0*(a1.xy+a5.xy) + K1*(a2.xy+a4.xy) + K2*a3.xy;
            const v2f h2b = K0*(a1.zw+a5.zw) + K1*(a2.zw+a4.zw) + K2*a3.zw;
            const float hcb = K0*(e1+e5) + K1*(e2+e4) + K2*e3;

            if (outv) {
                {
                    const v2f bP = K0*(pP0a+h1a) + K1*(pP1a+pP3a) + K2*pP2a;
                    const v2f bS = K0*(pQ0a+h2a) + K1*(pQ1a+pQ3a) + K2*pQ2a;
                    const float bC = K0*(pC0a+hca) + K1*(pC1a+pC3a) + K2*pC2a;
                    const float cross = bC - bP.x * bP.y;
                    const float vI = fmaxf(bS.x - bP.x * bP.x, 0.f) + 1e-5f;
                    const float vJ = fmaxf(bS.y - bP.y * bP.y, 0.f) + 1e-5f;
                    const float lncc = 1.0f - cross * rsqrtf(vI * vJ);
                    accL += lncc * mvala;
                    accM += mvala;
                }
                {
                    const v2f bP = K0*(pP0b+h1b) + K1*(pP1b+pP3b) + K2*pP2b;
                    const v2f bS = K0*(pQ0b+h2b) + K1*(pQ1b+pQ3b) + K2*pQ2b;
                    const float bC = K0*(pC0b+hcb) + K1*(pC1b+pC3b) + K2*pC2b;
                    const float cross = bC - bP.x * bP.y;
                    const float vI = fmaxf(bS.x - bP.x * bP.x, 0.f) + 1e-5f;
                    const float vJ = fmaxf(bS.y - bP.y * bP.y, 0.f) + 1e-5f;
                    const float lncc = 1.0f - cross * rsqrtf(vI * vJ);
                    accL += lncc * mvalb;
                    accM += mvalb;
                }
            }

            pP0a=pP1a; pP1a=pP2a; pP2a=pP3a; pP3a=h1a;
            pQ0a=pQ1a; pQ1a=pQ2a; pQ2a=pQ3a; pQ3a=h2a;
            pC0a=pC1a; pC1a=pC2a; pC2a=pC3a; pC3a=hca;
            pP0b=pP1b; pP1b=pP2b; pP2b=pP3b; pP3b=h1b;
            pQ0b=pQ1b; pQ1b=pQ2b; pQ2b=pQ3b; pQ3b=h2b;
            pC0b=pC1b; pC1b=pC2b; pC2b=pC3b; pC3b=hcb;
        }

        // LDS-only barrier: drain LDS but leave global prefetch in flight.
        asm volatile("s_waitcnt lgkmcnt(0)\n\ts_barrier" ::: "memory");
    }

    // ---- reduction ----
#pragma unroll
    for (int off = 32; off > 0; off >>= 1) {
        accL += __shfl_down(accL, off, 64);
        accM += __shfl_down(accM, off, 64);
    }
    const int wave = tid >> 6;
    if ((tid & 63) == 0) { redL[wave] = accL; redM[wave] = accM; }
    __syncthreads();
    if (tid == 0) {
        float sL = 0.f, sM = 0.f;
#pragma unroll
        for (int kk = 0; kk < 10; ++kk) { sL += redL[kk]; sM += redM[kk]; }
        atomicAdd(&acc[0], (double)sL);
        atomicAdd(&acc[1], (double)sM);
    }
}

__global__ void lncc_final(const double* __restrict__ acc, float* __restrict__ out)
{
    out[0] = (float)(acc[0] / (acc[1] + 1e-8));
}

extern "C" void kernel_launch(void* const* d_in, const int* in_sizes, int n_in,
                              void* d_out, int out_size, void* d_ws, size_t ws_size,
                              hipStream_t stream)
{
    const float* A = (const float*)d_in[0];
    const float* B = (const float*)d_in[1];
    const float* M = (const float*)d_in[2];
    double* acc = (double*)d_ws;

    hipMemsetAsync(d_ws, 0, 2 * sizeof(double), stream);

    dim3 grid(WW / TW, HH / TH, NB * NCHUNK);   // (7, 12, 16) = 1344 blocks
    dim3 block(640);
    hipLaunchKernelGGL(lncc_main, grid, block, 0, stream, A, B, M, acc);
    hipLaunchKernelGGL(lncc_final, dim3(1), dim3(1), 0, stream, acc, (float*)d_out);
}

// Round 10
// 229.898 us; speedup vs baseline: 1.1551x; 1.1551x over previous
//
#include <hip/hip_runtime.h>

// LNCC, separable 5-tap Gaussian (sigma=1), fused single pass.
// (N=2, C=1, D=160, H=192, W=224) fp32 -> scalar.
// R15: R11 champion base UNCHANGED (115-117us; 1344 blocks, 640 thr, 32x16x20
//      tile, dbuf LDS, packed-fp32 v2f, lgkm-only barrier, monolithic loop,
//      1 output row/thread r=tid>>5 -- balanced, VGPR 36) except the H-blur
//      tap fetch: lanes 0-31 of each output wave read the 6-row tap UNION
//      (half-wave ds_reads ~ half cost; R11 read 10 rows/wave, 4 redundant),
//      compute both rows' h packed on half lanes (same wave-VALU), then 5x
//      v_permlane32_swap_b32 (a.hi<->b.lo => a=[a.lo|b.lo]) hand row-(2w+1)
//      values to lanes 32-63. H-blur LDS 90->~54 cyc/wave; block LDS/iter
//      -20% on the binding pipe. Waves stay identical (R14 lesson: no
//      concentration), VGPR target <=48 (R14: >=52 costs 1/3 residency).

#define NB 2
#define DD 160
#define HH 192
#define WW 224
#define SH 224
#define SD (224*192)
#define SN (224*192*160)

#define TW 32
#define TH 16
#define ROWS (TH+4)          // 20
#define DCHUNK 20
#define NCHUNK (DD/DCHUNK)   // 8

#define K0 0.05448868f
#define K1 0.24420134f
#define K2 0.40261995f

typedef float v2f __attribute__((ext_vector_type(2)));
typedef float v4f __attribute__((ext_vector_type(4)));

__global__ __launch_bounds__(640) void lncc_main(
    const float* __restrict__ A, const float* __restrict__ B,
    const float* __restrict__ M, double* __restrict__ acc)
{
    __shared__ v2f  sIJ[2][ROWS][36];   // raw (I,J) + W halo, dbuf
    __shared__ v4f  wbA[2][ROWS][32];   // (bI,bJ,bII,bJJ), dbuf
    __shared__ float wbC[2][ROWS][32];  // bIJ, dbuf
    __shared__ float redL[10], redM[10];

    const int wt = blockIdx.x;           // 0..6
    const int ht = blockIdx.y;           // 0..11
    const int zz = blockIdx.z;           // 0..15
    const int n  = zz >> 3;
    const int dc = zz & 7;
    const int w0 = wt * TW, h0 = ht * TH, d0 = dc * DCHUNK;

    const float* __restrict__ Ai = A + (size_t)n * SN;
    const float* __restrict__ Bi = B + (size_t)n * SN;
    const float* __restrict__ Mi = M + (size_t)n * SN;

    const int tid = threadIdx.x;
    const int r   = tid >> 5;            // 0..19 (output row = h0 + r)
    const int c   = tid & 31;            // 0..31

    const int gh  = h0 + r - 2;
    const bool hv = (unsigned)gh < (unsigned)HH;
    const int ghc = hv ? gh : 0;
    const int hwm = ghc * SH + (w0 + c);          // 32-bit offsets
    const int gwl = w0 + c - 2, gwr = w0 + c + 2;
    const bool lv = hv && (c < 2)   && (gwl >= 0);
    const bool rv = hv && (c >= 30) && (gwr < WW);
    const bool anyh = lv || rv;
    const int hwh = ghc * SH + (lv ? gwl : (rv ? gwr : 0));
    const int mbase = (h0 + r) * SH + (w0 + c);

    // D-direction shift-register pipelines (oldest..newest), own row
    v2f pP0 = 0.f, pP1 = 0.f, pP2 = 0.f, pP3 = 0.f;   // (bI,bJ)
    v2f pQ0 = 0.f, pQ1 = 0.f, pQ2 = 0.f, pQ3 = 0.f;   // (bII,bJJ)
    float pC0 = 0.f, pC1 = 0.f, pC2 = 0.f, pC3 = 0.f; // bIJ
    float accL = 0.f, accM = 0.f;

    // prefetch registers for the slice staged at iteration k
    v2f nM = 0.f, nH = 0.f;
    {
        const int dd = d0 - 2;
        if (dd >= 0) {
            const int dof = dd * SD;
            if (hv)   { nM.x = Ai[dof + hwm]; nM.y = Bi[dof + hwm]; }
            if (anyh) { nH.x = Ai[dof + hwh]; nH.y = Bi[dof + hwh]; }
        }
    }

    const int rb = r & ~1;               // wave-pair base row
    const bool evenG = ((r & 1) == 0);   // lanes 0..31 of the wave

    const int NIT = DCHUNK + 6;          // 26
#pragma unroll 2
    for (int k = 0; k < NIT; ++k) {
        const int pw = k & 1;            // parity staged THIS iter
        const int px = pw ^ 1;

        // ---- W: stage prefetched raw slice (slices d0-2 .. d0+DCHUNK+1) ----
        if (k < DCHUNK + 4) {
            sIJ[pw][r][c + 2] = nM;
            if (c < 2)        sIJ[pw][r][c]     = nH;
            else if (c >= 30) sIJ[pw][r][c + 4] = nH;
        }

        // ---- prefetch slice k+1 ----
        nM = 0.f; nH = 0.f;
        {
            const int dd = d0 - 1 + k;
            if ((k + 1 < DCHUNK + 4) && (dd >= 0) && (dd < DD)) {
                const int dof = dd * SD;
                if (hv)   { nM.x = Ai[dof + hwm]; nM.y = Bi[dof + hwm]; }
                if (anyh) { nH.x = Ai[dof + hwh]; nH.y = Bi[dof + hwh]; }
            }
        }
        // ---- this iteration's mask value ----
        const int  dout = d0 - 6 + k;
        const bool outv = (k >= 6) && (r < TH);
        float mval = 0.f;
        if (outv) mval = Mi[dout * SD + mbase];

        // ---- X: W-blur of slice staged last iteration (packed I/J) ----
        if (k >= 1 && k <= DCHUNK + 4) {
            const v2f v0 = sIJ[px][r][c];
            const v2f v1 = sIJ[px][r][c + 1];
            const v2f v2 = sIJ[px][r][c + 2];
            const v2f v3 = sIJ[px][r][c + 3];
            const v2f v4 = sIJ[px][r][c + 4];
            const v2f b  = K0*(v0+v4) + K1*(v1+v3) + K2*v2;           // (bI,bJ)
            const v2f bs = K0*(v0*v0+v4*v4) + K1*(v1*v1+v3*v3) + K2*(v2*v2); // (bII,bJJ)
            const float bij = K0*(v0.x*v0.y+v4.x*v4.y) + K1*(v1.x*v1.y+v3.x*v3.y) + K2*(v2.x*v2.y);
            wbA[px][r][c] = (v4f){b.x, b.y, bs.x, bs.y};
            wbC[px][r][c] = bij;
        }

        // ---- Y: H-blur — even half reads 6-tap union, permlane distributes ----
        if (k >= 2 && r < TH) {          // wave-uniform (waves 0-7)
            float tIa, tJa, tIIa, tJJa, tca;   // row rb   results
            float tIb, tJb, tIIb, tJJb, tcb;   // row rb+1 results
            // zero-instruction definition (odd-lane contents never consumed:
            // the swap reads only a.lo/b.lo, which even lanes write)
            asm volatile("" : "=v"(tIa), "=v"(tJa), "=v"(tIIa), "=v"(tJJa), "=v"(tca),
                              "=v"(tIb), "=v"(tJb), "=v"(tIIb), "=v"(tJJb), "=v"(tcb));
            if (evenG) {
                const v4f a0 = wbA[pw][rb    ][c];
                const v4f a1 = wbA[pw][rb + 1][c];
                const v4f a2 = wbA[pw][rb + 2][c];
                const v4f a3 = wbA[pw][rb + 3][c];
                const v4f a4 = wbA[pw][rb + 4][c];
                const v4f a5 = wbA[pw][rb + 5][c];
                const float e0 = wbC[pw][rb    ][c];
                const float e1 = wbC[pw][rb + 1][c];
                const float e2 = wbC[pw][rb + 2][c];
                const float e3 = wbC[pw][rb + 3][c];
                const float e4 = wbC[pw][rb + 4][c];
                const float e5 = wbC[pw][rb + 5][c];

                const v2f h1a = K0*(a0.xy+a4.xy) + K1*(a1.xy+a3.xy) + K2*a2.xy;
                const v2f h2a = K0*(a0.zw+a4.zw) + K1*(a1.zw+a3.zw) + K2*a2.zw;
                const float hca = K0*(e0+e4) + K1*(e1+e3) + K2*e2;

                const v2f h1b = K0*(a1.xy+a5.xy) + K1*(a2.xy+a4.xy) + K2*a3.xy;
                const v2f h2b = K0*(a1.zw+a5.zw) + K1*(a2.zw+a4.zw) + K2*a3.zw;
                const float hcb = K0*(e1+e5) + K1*(e2+e4) + K2*e3;

                tIa = h1a.x; tJa = h1a.y; tIIa = h2a.x; tJJa = h2a.y; tca = hca;
                tIb = h1b.x; tJb = h1b.y; tIIb = h2b.x; tJJb = h2b.y; tcb = hcb;
            }
            // a.hi <-> b.lo  =>  a = [row-rb (lanes 0-31) | row-rb+1 (lanes 32-63)]
            asm("v_permlane32_swap_b32 %0, %1" : "+v"(tIa),  "+v"(tIb));
            asm("v_permlane32_swap_b32 %0, %1" : "+v"(tJa),  "+v"(tJb));
            asm("v_permlane32_swap_b32 %0, %1" : "+v"(tIIa), "+v"(tIIb));
            asm("v_permlane32_swap_b32 %0, %1" : "+v"(tJJa), "+v"(tJJb));
            asm("v_permlane32_swap_b32 %0, %1" : "+v"(tca),  "+v"(tcb));
            const v2f h1 = (v2f){tIa, tJa};    // (hI,hJ)   own row
            const v2f h2 = (v2f){tIIa, tJJa};  // (hII,hJJ) own row
            const float hc = tca;              // hIJ       own row

            if (outv) {
                const v2f bP = K0*(pP0+h1) + K1*(pP1+pP3) + K2*pP2;   // (bI,bJ)
                const v2f bS = K0*(pQ0+h2) + K1*(pQ1+pQ3) + K2*pQ2;   // (bII,bJJ)
                const float bC = K0*(pC0+hc) + K1*(pC1+pC3) + K2*pC2; // bIJ
                const float cross = bC - bP.x * bP.y;
                const float vI = fmaxf(bS.x - bP.x * bP.x, 0.f) + 1e-5f;
                const float vJ = fmaxf(bS.y - bP.y * bP.y, 0.f) + 1e-5f;
                const float lncc = 1.0f - cross * rsqrtf(vI * vJ);
                accL += lncc * mval;
                accM += mval;
            }

            pP0 = pP1; pP1 = pP2; pP2 = pP3; pP3 = h1;
            pQ0 = pQ1; pQ1 = pQ2; pQ2 = pQ3; pQ3 = h2;
            pC0 = pC1; pC1 = pC2; pC2 = pC3; pC3 = hc;
        }

        // LDS-only barrier: drain LDS but leave global prefetch in flight.
        asm volatile("s_waitcnt lgkmcnt(0)\n\ts_barrier" ::: "memory");
    }

    // ---- reduction ----
#pragma unroll
    for (int off = 32; off > 0; off >>= 1) {
        accL += __shfl_down(accL, off, 64);
        accM += __shfl_down(accM, off, 64);
    }
    const int wave = tid >> 6;
    if ((tid & 63) == 0) { redL[wave] = accL; redM[wave] = accM; }
    __syncthreads();
    if (tid == 0) {
        float sL = 0.f, sM = 0.f;
#pragma unroll
        for (int kk = 0; kk < 10; ++kk) { sL += redL[kk]; sM += redM[kk]; }
        atomicAdd(&acc[0], (double)sL);
        atomicAdd(&acc[1], (double)sM);
    }
}

__global__ void lncc_final(const double* __restrict__ acc, float* __restrict__ out)
{
    out[0] = (float)(acc[0] / (acc[1] + 1e-8));
}

extern "C" void kernel_launch(void* const* d_in, const int* in_sizes, int n_in,
                              void* d_out, int out_size, void* d_ws, size_t ws_size,
                              hipStream_t stream)
{
    const float* A = (const float*)d_in[0];
    const float* B = (const float*)d_in[1];
    const float* M = (const float*)d_in[2];
    double* acc = (double*)d_ws;

    hipMemsetAsync(d_ws, 0, 2 * sizeof(double), stream);

    dim3 grid(WW / TW, HH / TH, NB * NCHUNK);   // (7, 12, 16) = 1344 blocks
    dim3 block(640);
    hipLaunchKernelGGL(lncc_main, grid, block, 0, stream, A, B, M, acc);
    hipLaunchKernelGGL(lncc_final, dim3(1), dim3(1), 0, stream, acc, (float*)d_out);
}